// Round 1
// baseline (5228.909 us; speedup 1.0000x reference)
//
#include <hip/hip_runtime.h>
#include <hip/hip_bf16.h>
#include <cmath>
#include <stdint.h>

#define N 8192
#define LOGN 13
#define NMASK 8191
#define KEDGES 131072u
#define CAP 192
#define TILE 64
#define NT (N / TILE) /* 128 */
#define MAXDEG 64u
#define CCAP (1u << 20)
#define EQCAP 65536u

struct Scal {
  double s_same;
  double s_total;
  float w_same, w_diff;
  unsigned skip;
  unsigned binB, n_before, krem;
  unsigned binB2, krem2;
  unsigned tbits, n_eq_needed;
  unsigned dcount, ccount, eqcount;
};

// scratch layout inside d_out (bytes)
#define OFF_LAB 4096u       // u16[8192]
#define OFF_HIST 32768u     // u32[2048]
#define OFF_DEG 65536u      // u32[8192]
#define OFF_DEGN 98304u     // u32[8192]
#define OFF_THR 131072u     // f32[8192]
#define OFF_EQ 196608u      // u32[65536]
#define OFF_EQA 458752u     // u32[65536]
#define OFF_D (1u << 20)    // uint2[131072]
#define OFF_C (2u << 20)    // uint2[1<<20]
#define OFF_NBR (16u << 20) // u32[8192*CAP]
#define OFF_VAL (24u << 20) // f32[8192*CAP]
#define OFF_VALR (32u << 20)

__device__ __forceinline__ int laneId() { return threadIdx.x & 63; }

// wave-aggregated append; must be reached by all active lanes of the wave
__device__ __forceinline__ unsigned waveAppend(unsigned* ctr, bool pred) {
  unsigned long long m = __ballot(pred ? 1 : 0);
  unsigned base = 0;
  if (m) {
    int leader = __builtin_ctzll(m);
    int tot = __popcll(m);
    if (laneId() == leader) base = atomicAdd(ctr, (unsigned)tot);
    base = (unsigned)__shfl((int)base, leader, 64);
  }
  unsigned long long lt = m & ((1ull << laneId()) - 1ull);
  return base + (unsigned)__popcll(lt);
}

__global__ void k_labels(const float* __restrict__ lp, unsigned short* __restrict__ lab) {
  int i = blockIdx.x * blockDim.x + threadIdx.x;
  if (i >= N) return;
  const float* row = lp + (size_t)i * 16;
  float best = row[0];
  int bi = 0;
  for (int j = 1; j < 16; ++j) {
    float v = row[j];
    if (v > best) { best = v; bi = j; } // strict > : first max, matches jnp.argmax
  }
  lab[i] = (unsigned short)bi;
}

__global__ void k_mass(const float* __restrict__ A, const unsigned short* __restrict__ lab,
                       Scal* sc) {
  size_t tid = blockIdx.x * (size_t)blockDim.x + threadIdx.x;
  size_t nth = gridDim.x * (size_t)blockDim.x;
  double t_sum = 0.0, s_sum = 0.0;
  const float4* A4 = (const float4*)A;
  size_t n4 = (size_t)N * N / 4;
  for (size_t e = tid; e < n4; e += nth) {
    float4 a = A4[e];
    int i = (int)(e >> 11);
    int j0 = ((int)e & 2047) * 4;
    unsigned short li = lab[i];
    ushort4 lj = *(const ushort4*)(lab + j0);
    t_sum += (double)a.x + (double)a.y + (double)a.z + (double)a.w;
    if (li == lj.x && i != j0 + 0) s_sum += (double)a.x;
    if (li == lj.y && i != j0 + 1) s_sum += (double)a.y;
    if (li == lj.z && i != j0 + 2) s_sum += (double)a.z;
    if (li == lj.w && i != j0 + 3) s_sum += (double)a.w;
  }
  __shared__ double sh[512];
  int t = threadIdx.x;
  sh[t] = t_sum;
  sh[256 + t] = s_sum;
  __syncthreads();
  for (int off = 128; off > 0; off >>= 1) {
    if (t < off) { sh[t] += sh[t + off]; sh[256 + t] += sh[256 + t + off]; }
    __syncthreads();
  }
  if (t == 0) {
    atomicAdd(&sc->s_total, sh[0]);
    atomicAdd(&sc->s_same, sh[256]);
  }
}

__global__ void k_scal(Scal* sc) {
  double st = sc->s_total, ss = sc->s_same;
  double sd = st - ss;
  double cur = (st > 0.0) ? ss / st : 0.0;
  float curf = (float)cur;
  float ws = 0.7f / (curf + 1e-6f);
  ws = fminf(fmaxf(ws, 1.0f / 3.0f), 3.0f);
  float wd = 0.3f / ((1.0f - curf) + 1e-6f);
  wd = fminf(fmaxf(wd, 1.0f / 3.0f), 3.0f);
  int skip = (ss <= 1e-6) || (sd <= 1e-6) || (fabs(cur - 0.7) <= 0.05);
  sc->w_same = ws;
  sc->w_diff = wd;
  sc->skip = (unsigned)skip;
}

// h(i,j) for upper element: exact f32 replication of the reference elementwise chain
__device__ __forceinline__ float h_value(float aij, float aji, float w, int skip) {
  if (skip) return aij;
  float u = __fmul_rn(aij, w);
  float v = __fmul_rn(aji, w);
  return 0.5f * __fadd_rn(u, v);
}

__global__ __launch_bounds__(256) void k_hist(const float* __restrict__ A,
                                              const unsigned short* __restrict__ lab,
                                              const Scal* __restrict__ sc,
                                              unsigned* __restrict__ ghist) {
  int bI = blockIdx.x, bJ = blockIdx.y;
  if (bJ < bI) return;
  __shared__ float A2[TILE][TILE + 1];
  __shared__ unsigned short labr[TILE], labc[TILE];
  __shared__ unsigned hist[2048];
  int t = threadIdx.x;
  for (int b = t; b < 2048; b += 256) hist[b] = 0;
  if (t < TILE) { labr[t] = lab[bI * TILE + t]; labc[t] = lab[bJ * TILE + t]; }
  for (int chunk = t; chunk < TILE * TILE / 4; chunk += 256) {
    int r = chunk >> 4;
    int c4 = (chunk & 15) << 2;
    float4 g = *(const float4*)(A + (((size_t)(bJ * TILE + r)) << LOGN) + bI * TILE + c4);
    A2[r][c4 + 0] = g.x; A2[r][c4 + 1] = g.y; A2[r][c4 + 2] = g.z; A2[r][c4 + 3] = g.w;
  }
  __syncthreads();
  float w_s = sc->w_same, w_d = sc->w_diff;
  int skip = (int)sc->skip;
  for (int sub = 0; sub < 4; ++sub) {
    int id4 = sub * 256 + t;
    int r = id4 >> 4;
    int c4 = (id4 & 15) << 2;
    float4 a1 = *(const float4*)(A + (((size_t)(bI * TILE + r)) << LOGN) + bJ * TILE + c4);
    float a1v[4] = {a1.x, a1.y, a1.z, a1.w};
#pragma unroll
    for (int k = 0; k < 4; ++k) {
      int c = c4 + k;
      bool valid = !(bI == bJ && c <= r);
      float w = (labr[r] == labc[c]) ? w_s : w_d;
      float h = h_value(a1v[k], A2[c][r], w, skip);
      if (valid) atomicAdd(&hist[__float_as_uint(h) >> 21], 1u);
    }
  }
  __syncthreads();
  for (int b = t; b < 2048; b += 256) {
    unsigned v = hist[b];
    if (v) atomicAdd(&ghist[b], v);
  }
}

__global__ void k_findbin(const unsigned* __restrict__ ghist, Scal* sc) {
  if (threadIdx.x) return;
  unsigned cum = 0;
  for (int b = 2047; b >= 0; --b) {
    unsigned c = ghist[b];
    if (cum + c >= KEDGES) {
      sc->binB = (unsigned)b;
      sc->n_before = cum;
      sc->krem = KEDGES - cum;
      return;
    }
    cum += c;
  }
}

__global__ __launch_bounds__(256) void k_emit(const float* __restrict__ A,
                                              const unsigned short* __restrict__ lab,
                                              Scal* sc, uint2* __restrict__ Dl,
                                              uint2* __restrict__ Cl) {
  int bI = blockIdx.x, bJ = blockIdx.y;
  if (bJ < bI) return;
  __shared__ float A2[TILE][TILE + 1];
  __shared__ unsigned short labr[TILE], labc[TILE];
  int t = threadIdx.x;
  if (t < TILE) { labr[t] = lab[bI * TILE + t]; labc[t] = lab[bJ * TILE + t]; }
  for (int chunk = t; chunk < TILE * TILE / 4; chunk += 256) {
    int r = chunk >> 4;
    int c4 = (chunk & 15) << 2;
    float4 g = *(const float4*)(A + (((size_t)(bJ * TILE + r)) << LOGN) + bI * TILE + c4);
    A2[r][c4 + 0] = g.x; A2[r][c4 + 1] = g.y; A2[r][c4 + 2] = g.z; A2[r][c4 + 3] = g.w;
  }
  __syncthreads();
  float w_s = sc->w_same, w_d = sc->w_diff;
  int skip = (int)sc->skip;
  unsigned B = sc->binB;
  for (int sub = 0; sub < 4; ++sub) {
    int id4 = sub * 256 + t;
    int r = id4 >> 4;
    int c4 = (id4 & 15) << 2;
    float4 a1 = *(const float4*)(A + (((size_t)(bI * TILE + r)) << LOGN) + bJ * TILE + c4);
    float a1v[4] = {a1.x, a1.y, a1.z, a1.w};
#pragma unroll
    for (int k = 0; k < 4; ++k) {
      int c = c4 + k;
      bool valid = !(bI == bJ && c <= r);
      float w = (labr[r] == labc[c]) ? w_s : w_d;
      float h = h_value(a1v[k], A2[c][r], w, skip);
      unsigned bits = __float_as_uint(h);
      unsigned bin = bits >> 21;
      unsigned fi = ((unsigned)(bI * TILE + r) << LOGN) | (unsigned)(bJ * TILE + c);
      bool isD = valid && (bin > B);
      bool isC = valid && (bin == B);
      unsigned pos = waveAppend(&sc->dcount, isD);
      if (isD && pos < KEDGES) Dl[pos] = make_uint2(fi, bits);
      pos = waveAppend(&sc->ccount, isC);
      if (isC && pos < CCAP) Cl[pos] = make_uint2(fi, bits);
    }
  }
}

__global__ void k_midhist(const uint2* __restrict__ Cl, const Scal* __restrict__ sc,
                          unsigned* __restrict__ hist) {
  unsigned n = sc->ccount;
  if (n > CCAP) n = CCAP;
  for (unsigned e = blockIdx.x * blockDim.x + threadIdx.x; e < n; e += gridDim.x * blockDim.x)
    atomicAdd(&hist[(Cl[e].y >> 10) & 0x7FFu], 1u);
}

__global__ void k_findmid(const unsigned* __restrict__ hist, Scal* sc) {
  if (threadIdx.x) return;
  unsigned kr = sc->krem, cum = 0;
  for (int b = 2047; b >= 0; --b) {
    unsigned c = hist[b];
    if (cum + c >= kr) {
      sc->binB2 = (unsigned)b;
      sc->krem2 = kr - cum;
      return;
    }
    cum += c;
  }
}

__global__ void k_lowhist(const uint2* __restrict__ Cl, const Scal* __restrict__ sc,
                          unsigned* __restrict__ hist) {
  unsigned n = sc->ccount;
  if (n > CCAP) n = CCAP;
  unsigned B2 = sc->binB2;
  for (unsigned e = blockIdx.x * blockDim.x + threadIdx.x; e < n; e += gridDim.x * blockDim.x) {
    unsigned b = Cl[e].y;
    if (((b >> 10) & 0x7FFu) == B2) atomicAdd(&hist[b & 0x3FFu], 1u);
  }
}

__global__ void k_findlow(const unsigned* __restrict__ hist, Scal* sc) {
  if (threadIdx.x) return;
  unsigned kr = sc->krem2, cum = 0;
  for (int b = 1023; b >= 0; --b) {
    unsigned c = hist[b];
    if (cum + c >= kr) {
      sc->tbits = (sc->binB << 21) | (sc->binB2 << 10) | (unsigned)b;
      sc->n_eq_needed = kr - cum;
      return;
    }
    cum += c;
  }
}

__global__ void k_eqcollect(const uint2* __restrict__ Cl, Scal* sc, unsigned* __restrict__ EQ) {
  unsigned n = sc->ccount;
  if (n > CCAP) n = CCAP;
  unsigned T = sc->tbits;
  for (unsigned e = blockIdx.x * blockDim.x + threadIdx.x; e < n; e += gridDim.x * blockDim.x) {
    bool pred = (Cl[e].y == T);
    unsigned pos = waveAppend(&sc->eqcount, pred);
    if (pred && pos < EQCAP) EQ[pos] = Cl[e].x;
  }
}

__global__ void k_eqrank(const unsigned* __restrict__ EQ, const Scal* __restrict__ sc,
                         unsigned* __restrict__ EQA) {
  unsigned n = sc->eqcount;
  if (n > EQCAP) n = EQCAP;
  unsigned need = sc->n_eq_needed;
  for (unsigned e = threadIdx.x; e < n; e += blockDim.x) {
    unsigned my = EQ[e], rank = 0;
    for (unsigned f = 0; f < n; ++f) rank += (EQ[f] < my) ? 1u : 0u;
    EQA[e] = (rank < need) ? 1u : 0u;
  }
}

__global__ void k_build(const float* __restrict__ A, const uint2* __restrict__ Dl,
                        const uint2* __restrict__ Cl, const unsigned* __restrict__ EQ,
                        const unsigned* __restrict__ EQA, const Scal* __restrict__ sc,
                        unsigned* __restrict__ deg, unsigned* __restrict__ nbr,
                        float* __restrict__ val, float* __restrict__ valr) {
  unsigned dn = sc->dcount; if (dn > KEDGES) dn = KEDGES;
  unsigned cn = sc->ccount; if (cn > CCAP) cn = CCAP;
  unsigned en = sc->eqcount; if (en > EQCAP) en = EQCAP;
  unsigned T = sc->tbits;
  int skip = (int)sc->skip;
  unsigned tot = dn + cn + en;
  for (unsigned t = blockIdx.x * blockDim.x + threadIdx.x; t < tot; t += gridDim.x * blockDim.x) {
    unsigned idx, bits;
    bool acc;
    if (t < dn) {
      uint2 e = Dl[t]; idx = e.x; bits = e.y; acc = true;
    } else if (t < dn + cn) {
      uint2 e = Cl[t - dn]; idx = e.x; bits = e.y; acc = (bits > T);
    } else {
      unsigned q = t - dn - cn; idx = EQ[q]; bits = T; acc = (EQA[q] != 0);
    }
    if (!acc) continue;
    int i = (int)(idx >> LOGN), j = (int)(idx & NMASK);
    float v = __uint_as_float(bits);
    float vf = v, vr = v;
    if (skip) vr = A[(size_t)j * N + i];
    unsigned pi = atomicAdd(&deg[i], 1u);
    if (pi < CAP) { nbr[i * CAP + pi] = (unsigned)j; val[i * CAP + pi] = vf; valr[i * CAP + pi] = vr; }
    unsigned pj = atomicAdd(&deg[j], 1u);
    if (pj < CAP) { nbr[j * CAP + pj] = (unsigned)i; val[j * CAP + pj] = vr; valr[j * CAP + pj] = vf; }
  }
}

__global__ void k_thresh(const unsigned* __restrict__ deg, const float* __restrict__ val,
                         float* __restrict__ thr) {
  int node = blockIdx.x * (blockDim.x >> 6) + (threadIdx.x >> 6);
  if (node >= N) return;
  int lane = threadIdx.x & 63;
  unsigned d = deg[node];
  if (d <= MAXDEG) {
    if (!lane) thr[node] = -INFINITY;
    return;
  }
  unsigned dc = d < CAP ? d : CAP;
  const float* v = val + (size_t)node * CAP;
  float best = INFINITY;
  for (unsigned s = lane; s < dc; s += 64) {
    float vs = v[s];
    unsigned cnt = 0;
    for (unsigned u = 0; u < dc; ++u) cnt += (v[u] > vs) ? 1u : 0u;
    if (cnt <= MAXDEG - 1) best = fminf(best, vs);
  }
  for (int off = 32; off; off >>= 1) best = fminf(best, __shfl_xor(best, off, 64));
  if (!lane) thr[node] = best;
}

__global__ void k_filter(const unsigned* __restrict__ deg, const float* __restrict__ thr,
                         unsigned* __restrict__ nbr, float* __restrict__ val,
                         float* __restrict__ valr, unsigned* __restrict__ degn) {
  int node = blockIdx.x * (blockDim.x >> 6) + (threadIdx.x >> 6);
  if (node >= N) return;
  int lane = threadIdx.x & 63;
  unsigned d = deg[node];
  unsigned dc = d < CAP ? d : CAP;
  float ti = thr[node];
  bool iok = (d <= MAXDEG);
  unsigned* nb = nbr + (size_t)node * CAP;
  float* vv = val + (size_t)node * CAP;
  float* vr = valr + (size_t)node * CAP;
  unsigned base = 0;
  for (unsigned r0 = 0; r0 < dc; r0 += 64) {
    unsigned s = r0 + lane;
    bool act = s < dc;
    unsigned j = 0;
    float v = 0.f, w = 0.f;
    bool keep = false;
    if (act) {
      j = nb[s]; v = vv[s]; w = vr[s];
      unsigned dj = deg[j];
      keep = (iok || v >= ti) && (dj <= MAXDEG || w >= thr[j]);
    }
    unsigned long long m = __ballot(keep ? 1 : 0);
    unsigned pos = base + (unsigned)__popcll(m & ((1ull << lane) - 1ull));
    if (keep) { nb[pos] = j; vv[pos] = v; vr[pos] = w; }
    base += (unsigned)__popcll(m);
  }
  if (!lane) degn[node] = base;
}

__global__ void k_copydeg(const unsigned* __restrict__ degn, unsigned* __restrict__ deg) {
  int i = blockIdx.x * blockDim.x + threadIdx.x;
  if (i < N) deg[i] = degn[i];
}

__global__ void k_compact(const unsigned* __restrict__ deg, const unsigned* __restrict__ nbr,
                          unsigned* __restrict__ wcnt, unsigned* __restrict__ wedges) {
  int node = blockIdx.x;
  int s = threadIdx.x; // 192 threads
  unsigned d = deg[node];
  if (d > CAP) d = CAP;
  bool pred = false;
  unsigned j = 0;
  if ((unsigned)s < d) {
    j = nbr[(size_t)node * CAP + s];
    pred = (j > (unsigned)node);
  }
  unsigned pos = waveAppend(wcnt, pred);
  if (pred && pos < KEDGES) wedges[pos] = ((unsigned)node << LOGN) | j;
}

__global__ void k_scatter(const unsigned* __restrict__ wcnt, const unsigned* __restrict__ wedges,
                          float* __restrict__ out) {
  unsigned t = blockIdx.x * blockDim.x + threadIdx.x;
  unsigned n = *wcnt;
  if (n > KEDGES) n = KEDGES;
  if (t < n) {
    unsigned e = wedges[t];
    unsigned i = e >> LOGN, j = e & NMASK;
    out[(size_t)i * N + j] = 1.0f;
    out[(size_t)j * N + i] = 1.0f;
  }
}

extern "C" void kernel_launch(void* const* d_in, const int* in_sizes, int n_in,
                              void* d_out, int out_size, void* d_ws, size_t ws_size,
                              hipStream_t stream) {
  (void)in_sizes; (void)n_in; (void)out_size;
  const float* A = (const float*)d_in[0];
  const float* LP = (const float*)d_in[1];
  float* out = (float*)d_out;
  char* B8 = (char*)d_out;

  Scal* sc = (Scal*)B8;
  unsigned short* lab = (unsigned short*)(B8 + OFF_LAB);
  unsigned* hist = (unsigned*)(B8 + OFF_HIST);
  unsigned* deg = (unsigned*)(B8 + OFF_DEG);
  unsigned* degn = (unsigned*)(B8 + OFF_DEGN);
  float* thr = (float*)(B8 + OFF_THR);
  unsigned* EQ = (unsigned*)(B8 + OFF_EQ);
  unsigned* EQA = (unsigned*)(B8 + OFF_EQA);
  uint2* Dl = (uint2*)(B8 + OFF_D);
  uint2* Cl = (uint2*)(B8 + OFF_C);
  unsigned* nbr = (unsigned*)(B8 + OFF_NBR);
  float* val = (float*)(B8 + OFF_VAL);
  float* valr = (float*)(B8 + OFF_VALR);

  // final edge list: prefer d_ws; fall back to the tail of d_in[0] (A is not
  // read after k_build, and the harness restores inputs before every launch)
  bool ws_ok = ws_size >= (size_t)(1024 + 4 * KEDGES);
  unsigned* wcnt = ws_ok ? (unsigned*)d_ws : (unsigned*)((char*)d_in[0] + (200u << 20));
  unsigned* wedges = wcnt + 256;

  hipMemsetAsync(B8, 0, 4096, stream);                  // scalars
  hipMemsetAsync(B8 + OFF_HIST, 0, 8192, stream);       // histogram
  hipMemsetAsync(B8 + OFF_DEG, 0, 32768, stream);       // degree counters
  hipMemsetAsync(wcnt, 0, 1024, stream);                // final edge counter

  k_labels<<<32, 256, 0, stream>>>(LP, lab);
  k_mass<<<4096, 256, 0, stream>>>(A, lab, sc);
  k_scal<<<1, 1, 0, stream>>>(sc);
  k_hist<<<dim3(NT, NT), 256, 0, stream>>>(A, lab, sc, hist);
  k_findbin<<<1, 64, 0, stream>>>(hist, sc);
  k_emit<<<dim3(NT, NT), 256, 0, stream>>>(A, lab, sc, Dl, Cl);
  hipMemsetAsync(B8 + OFF_HIST, 0, 8192, stream);
  k_midhist<<<1024, 256, 0, stream>>>(Cl, sc, hist);
  k_findmid<<<1, 64, 0, stream>>>(hist, sc);
  hipMemsetAsync(B8 + OFF_HIST, 0, 8192, stream);
  k_lowhist<<<1024, 256, 0, stream>>>(Cl, sc, hist);
  k_findlow<<<1, 64, 0, stream>>>(hist, sc);
  k_eqcollect<<<1024, 256, 0, stream>>>(Cl, sc, EQ);
  k_eqrank<<<1, 256, 0, stream>>>(EQ, sc, EQA);
  k_build<<<2048, 256, 0, stream>>>(A, Dl, Cl, EQ, EQA, sc, deg, nbr, val, valr);
  for (int it = 0; it < 10; ++it) {
    k_thresh<<<2048, 256, 0, stream>>>(deg, val, thr);
    k_filter<<<2048, 256, 0, stream>>>(deg, thr, nbr, val, valr, degn);
    k_copydeg<<<32, 256, 0, stream>>>(degn, deg);
  }
  k_compact<<<N, CAP, 0, stream>>>(deg, nbr, wcnt, wedges);
  hipMemsetAsync(d_out, 0, (size_t)N * N * sizeof(float), stream);
  k_scatter<<<(KEDGES + 255) / 256, 256, 0, stream>>>(wcnt, wedges, out);
}

// Round 3
// 1325.565 us; speedup vs baseline: 3.9447x; 3.9447x over previous
//
#include <hip/hip_runtime.h>
#include <hip/hip_bf16.h>
#include <cmath>
#include <stdint.h>

#define N 8192
#define LOGN 13
#define NMASK 8191
#define KEDGES 131072u
#define CAP 192
#define TILE 64
#define NT (N / TILE) /* 128 */
#define MAXDEG 64u
#define CCAP (1u << 20)
#define EQCAP 65536u

struct Scal {
  double s_same;
  double s_total;
  float w_same, w_diff;
  unsigned skip;
  unsigned binB, n_before, krem;
  unsigned binB2, krem2;
  unsigned tbits, n_eq_needed;
  unsigned dcount, ccount, eqcount;
};

// scratch layout inside d_out (bytes)
#define OFF_LAB 4096u       // u16[8192]
#define OFF_HIST 32768u     // u32[2048]
#define OFF_DEG 65536u      // u32[8192]
#define OFF_DEGN 98304u     // u32[8192]
#define OFF_THR 131072u     // f32[8192]
#define OFF_EQ 196608u      // u32[65536]
#define OFF_EQA 458752u     // u32[65536]
#define OFF_D (1u << 20)    // uint2[131072]
#define OFF_C (2u << 20)    // uint2[1<<20]
#define OFF_NBR (16u << 20) // u32[8192*CAP]
#define OFF_VAL (24u << 20) // f32[8192*CAP]
#define OFF_VALR (32u << 20)

__device__ __forceinline__ int laneId() { return threadIdx.x & 63; }

// wave-aggregated append; must be reached by all active lanes of the wave
__device__ __forceinline__ unsigned waveAppend(unsigned* ctr, bool pred) {
  unsigned long long m = __ballot(pred ? 1 : 0);
  unsigned base = 0;
  if (m) {
    int leader = __builtin_ctzll(m);
    int tot = __popcll(m);
    if (laneId() == leader) base = atomicAdd(ctr, (unsigned)tot);
    base = (unsigned)__shfl((int)base, leader, 64);
  }
  unsigned long long lt = m & ((1ull << laneId()) - 1ull);
  return base + (unsigned)__popcll(lt);
}

__global__ void k_labels(const float* __restrict__ lp, unsigned short* __restrict__ lab) {
  int i = blockIdx.x * blockDim.x + threadIdx.x;
  if (i >= N) return;
  const float* row = lp + (size_t)i * 16;
  float best = row[0];
  int bi = 0;
  for (int j = 1; j < 16; ++j) {
    float v = row[j];
    if (v > best) { best = v; bi = j; } // strict > : first max, matches jnp.argmax
  }
  lab[i] = (unsigned short)bi;
}

__global__ void k_mass(const float* __restrict__ A, const unsigned short* __restrict__ lab,
                       Scal* sc) {
  size_t tid = blockIdx.x * (size_t)blockDim.x + threadIdx.x;
  size_t nth = gridDim.x * (size_t)blockDim.x;
  double t_sum = 0.0, s_sum = 0.0;
  const float4* A4 = (const float4*)A;
  size_t n4 = (size_t)N * N / 4;
  for (size_t e = tid; e < n4; e += nth) {
    float4 a = A4[e];
    int i = (int)(e >> 11);
    int j0 = ((int)e & 2047) * 4;
    unsigned short li = lab[i];
    ushort4 lj = *(const ushort4*)(lab + j0);
    t_sum += (double)a.x + (double)a.y + (double)a.z + (double)a.w;
    if (li == lj.x && i != j0 + 0) s_sum += (double)a.x;
    if (li == lj.y && i != j0 + 1) s_sum += (double)a.y;
    if (li == lj.z && i != j0 + 2) s_sum += (double)a.z;
    if (li == lj.w && i != j0 + 3) s_sum += (double)a.w;
  }
  __shared__ double sh[512];
  int t = threadIdx.x;
  sh[t] = t_sum;
  sh[256 + t] = s_sum;
  __syncthreads();
  for (int off = 128; off > 0; off >>= 1) {
    if (t < off) { sh[t] += sh[t + off]; sh[256 + t] += sh[256 + t + off]; }
    __syncthreads();
  }
  if (t == 0) {
    atomicAdd(&sc->s_total, sh[0]);
    atomicAdd(&sc->s_same, sh[256]);
  }
}

__global__ void k_scal(Scal* sc) {
  double st = sc->s_total, ss = sc->s_same;
  double sd = st - ss;
  double cur = (st > 0.0) ? ss / st : 0.0;
  float curf = (float)cur;
  float ws = 0.7f / (curf + 1e-6f);
  ws = fminf(fmaxf(ws, 1.0f / 3.0f), 3.0f);
  float wd = 0.3f / ((1.0f - curf) + 1e-6f);
  wd = fminf(fmaxf(wd, 1.0f / 3.0f), 3.0f);
  int skip = (ss <= 1e-6) || (sd <= 1e-6) || (fabs(cur - 0.7) <= 0.05);
  sc->w_same = ws;
  sc->w_diff = wd;
  sc->skip = (unsigned)skip;
}

// h(i,j) for upper element: exact f32 replication of the reference elementwise chain
__device__ __forceinline__ float h_value(float aij, float aji, float w, int skip) {
  if (skip) return aij;
  float u = __fmul_rn(aij, w);
  float v = __fmul_rn(aji, w);
  return 0.5f * __fadd_rn(u, v);
}

__global__ __launch_bounds__(256) void k_hist(const float* __restrict__ A,
                                              const unsigned short* __restrict__ lab,
                                              const Scal* __restrict__ sc,
                                              unsigned* __restrict__ ghist) {
  int bI = blockIdx.x, bJ = blockIdx.y;
  if (bJ < bI) return;
  __shared__ float A2[TILE][TILE + 1];
  __shared__ unsigned short labr[TILE], labc[TILE];
  __shared__ unsigned hist[2048];
  int t = threadIdx.x;
  for (int b = t; b < 2048; b += 256) hist[b] = 0;
  if (t < TILE) { labr[t] = lab[bI * TILE + t]; labc[t] = lab[bJ * TILE + t]; }
  for (int chunk = t; chunk < TILE * TILE / 4; chunk += 256) {
    int r = chunk >> 4;
    int c4 = (chunk & 15) << 2;
    float4 g = *(const float4*)(A + (((size_t)(bJ * TILE + r)) << LOGN) + bI * TILE + c4);
    A2[r][c4 + 0] = g.x; A2[r][c4 + 1] = g.y; A2[r][c4 + 2] = g.z; A2[r][c4 + 3] = g.w;
  }
  __syncthreads();
  float w_s = sc->w_same, w_d = sc->w_diff;
  int skip = (int)sc->skip;
  for (int sub = 0; sub < 4; ++sub) {
    int id4 = sub * 256 + t;
    int r = id4 >> 4;
    int c4 = (id4 & 15) << 2;
    float4 a1 = *(const float4*)(A + (((size_t)(bI * TILE + r)) << LOGN) + bJ * TILE + c4);
    float a1v[4] = {a1.x, a1.y, a1.z, a1.w};
#pragma unroll
    for (int k = 0; k < 4; ++k) {
      int c = c4 + k;
      bool valid = !(bI == bJ && c <= r);
      float w = (labr[r] == labc[c]) ? w_s : w_d;
      float h = h_value(a1v[k], A2[c][r], w, skip);
      if (valid) atomicAdd(&hist[__float_as_uint(h) >> 21], 1u);
    }
  }
  __syncthreads();
  for (int b = t; b < 2048; b += 256) {
    unsigned v = hist[b];
    if (v) atomicAdd(&ghist[b], v);
  }
}

__global__ void k_findbin(const unsigned* __restrict__ ghist, Scal* sc) {
  if (threadIdx.x) return;
  unsigned cum = 0;
  for (int b = 2047; b >= 0; --b) {
    unsigned c = ghist[b];
    if (cum + c >= KEDGES) {
      sc->binB = (unsigned)b;
      sc->n_before = cum;
      sc->krem = KEDGES - cum;
      return;
    }
    cum += c;
  }
}

// Per-block LDS staging of candidates; exactly 2 global atomics per block.
// Order within Dl/Cl is irrelevant (selection uses values + index ranks only).
__global__ __launch_bounds__(256) void k_emit(const float* __restrict__ A,
                                              const unsigned short* __restrict__ lab,
                                              Scal* sc, uint2* __restrict__ Dl,
                                              uint2* __restrict__ Cl) {
  int bI = blockIdx.x, bJ = blockIdx.y;
  if (bJ < bI) return;
  __shared__ float A2[TILE][TILE + 1];
  __shared__ unsigned short labr[TILE], labc[TILE];
  __shared__ uint2 stage[TILE * TILE]; // D from front, C from back; isD/isC disjoint
  __shared__ unsigned cntD, cntC, baseD, baseC;
  int t = threadIdx.x;
  if (t == 0) { cntD = 0; cntC = 0; }
  if (t < TILE) { labr[t] = lab[bI * TILE + t]; labc[t] = lab[bJ * TILE + t]; }
  for (int chunk = t; chunk < TILE * TILE / 4; chunk += 256) {
    int r = chunk >> 4;
    int c4 = (chunk & 15) << 2;
    float4 g = *(const float4*)(A + (((size_t)(bJ * TILE + r)) << LOGN) + bI * TILE + c4);
    A2[r][c4 + 0] = g.x; A2[r][c4 + 1] = g.y; A2[r][c4 + 2] = g.z; A2[r][c4 + 3] = g.w;
  }
  __syncthreads();
  float w_s = sc->w_same, w_d = sc->w_diff;
  int skip = (int)sc->skip;
  unsigned B = sc->binB;
  for (int sub = 0; sub < 4; ++sub) {
    int id4 = sub * 256 + t;
    int r = id4 >> 4;
    int c4 = (id4 & 15) << 2;
    float4 a1 = *(const float4*)(A + (((size_t)(bI * TILE + r)) << LOGN) + bJ * TILE + c4);
    float a1v[4] = {a1.x, a1.y, a1.z, a1.w};
#pragma unroll
    for (int k = 0; k < 4; ++k) {
      int c = c4 + k;
      bool valid = !(bI == bJ && c <= r);
      float w = (labr[r] == labc[c]) ? w_s : w_d;
      float h = h_value(a1v[k], A2[c][r], w, skip);
      unsigned bits = __float_as_uint(h);
      unsigned bin = bits >> 21;
      unsigned fi = ((unsigned)(bI * TILE + r) << LOGN) | (unsigned)(bJ * TILE + c);
      if (valid && bin > B) {
        unsigned p = atomicAdd(&cntD, 1u);
        stage[p] = make_uint2(fi, bits);
      } else if (valid && bin == B) {
        unsigned p = atomicAdd(&cntC, 1u);
        stage[TILE * TILE - 1 - p] = make_uint2(fi, bits);
      }
    }
  }
  __syncthreads();
  if (t == 0) {
    baseD = cntD ? atomicAdd(&sc->dcount, cntD) : 0u;
    baseC = cntC ? atomicAdd(&sc->ccount, cntC) : 0u;
  }
  __syncthreads();
  unsigned nD = cntD, nC = cntC, bD = baseD, bC = baseC;
  for (unsigned p = t; p < nD; p += 256) {
    unsigned g = bD + p;
    if (g < KEDGES) Dl[g] = stage[p];
  }
  for (unsigned p = t; p < nC; p += 256) {
    unsigned g = bC + p;
    if (g < CCAP) Cl[g] = stage[TILE * TILE - 1 - p];
  }
}

__global__ void k_midhist(const uint2* __restrict__ Cl, const Scal* __restrict__ sc,
                          unsigned* __restrict__ hist) {
  unsigned n = sc->ccount;
  if (n > CCAP) n = CCAP;
  for (unsigned e = blockIdx.x * blockDim.x + threadIdx.x; e < n; e += gridDim.x * blockDim.x)
    atomicAdd(&hist[(Cl[e].y >> 10) & 0x7FFu], 1u);
}

__global__ void k_findmid(const unsigned* __restrict__ hist, Scal* sc) {
  if (threadIdx.x) return;
  unsigned kr = sc->krem, cum = 0;
  for (int b = 2047; b >= 0; --b) {
    unsigned c = hist[b];
    if (cum + c >= kr) {
      sc->binB2 = (unsigned)b;
      sc->krem2 = kr - cum;
      return;
    }
    cum += c;
  }
}

__global__ void k_lowhist(const uint2* __restrict__ Cl, const Scal* __restrict__ sc,
                          unsigned* __restrict__ hist) {
  unsigned n = sc->ccount;
  if (n > CCAP) n = CCAP;
  unsigned B2 = sc->binB2;
  for (unsigned e = blockIdx.x * blockDim.x + threadIdx.x; e < n; e += gridDim.x * blockDim.x) {
    unsigned b = Cl[e].y;
    if (((b >> 10) & 0x7FFu) == B2) atomicAdd(&hist[b & 0x3FFu], 1u);
  }
}

__global__ void k_findlow(const unsigned* __restrict__ hist, Scal* sc) {
  if (threadIdx.x) return;
  unsigned kr = sc->krem2, cum = 0;
  for (int b = 1023; b >= 0; --b) {
    unsigned c = hist[b];
    if (cum + c >= kr) {
      sc->tbits = (sc->binB << 21) | (sc->binB2 << 10) | (unsigned)b;
      sc->n_eq_needed = kr - cum;
      return;
    }
    cum += c;
  }
}

__global__ void k_eqcollect(const uint2* __restrict__ Cl, Scal* sc, unsigned* __restrict__ EQ) {
  unsigned n = sc->ccount;
  if (n > CCAP) n = CCAP;
  unsigned T = sc->tbits;
  for (unsigned e = blockIdx.x * blockDim.x + threadIdx.x; e < n; e += gridDim.x * blockDim.x) {
    bool pred = (Cl[e].y == T);
    unsigned pos = waveAppend(&sc->eqcount, pred);
    if (pred && pos < EQCAP) EQ[pos] = Cl[e].x;
  }
}

__global__ void k_eqrank(const unsigned* __restrict__ EQ, const Scal* __restrict__ sc,
                         unsigned* __restrict__ EQA) {
  unsigned n = sc->eqcount;
  if (n > EQCAP) n = EQCAP;
  unsigned need = sc->n_eq_needed;
  for (unsigned e = threadIdx.x; e < n; e += blockDim.x) {
    unsigned my = EQ[e], rank = 0;
    for (unsigned f = 0; f < n; ++f) rank += (EQ[f] < my) ? 1u : 0u;
    EQA[e] = (rank < need) ? 1u : 0u;
  }
}

__global__ void k_build(const float* __restrict__ A, const uint2* __restrict__ Dl,
                        const uint2* __restrict__ Cl, const unsigned* __restrict__ EQ,
                        const unsigned* __restrict__ EQA, const Scal* __restrict__ sc,
                        unsigned* __restrict__ deg, unsigned* __restrict__ nbr,
                        float* __restrict__ val, float* __restrict__ valr) {
  unsigned dn = sc->dcount; if (dn > KEDGES) dn = KEDGES;
  unsigned cn = sc->ccount; if (cn > CCAP) cn = CCAP;
  unsigned en = sc->eqcount; if (en > EQCAP) en = EQCAP;
  unsigned T = sc->tbits;
  int skip = (int)sc->skip;
  unsigned tot = dn + cn + en;
  for (unsigned t = blockIdx.x * blockDim.x + threadIdx.x; t < tot; t += gridDim.x * blockDim.x) {
    unsigned idx, bits;
    bool acc;
    if (t < dn) {
      uint2 e = Dl[t]; idx = e.x; bits = e.y; acc = true;
    } else if (t < dn + cn) {
      uint2 e = Cl[t - dn]; idx = e.x; bits = e.y; acc = (bits > T);
    } else {
      unsigned q = t - dn - cn; idx = EQ[q]; bits = T; acc = (EQA[q] != 0);
    }
    if (!acc) continue;
    int i = (int)(idx >> LOGN), j = (int)(idx & NMASK);
    float v = __uint_as_float(bits);
    float vf = v, vr = v;
    if (skip) vr = A[(size_t)j * N + i];
    unsigned pi = atomicAdd(&deg[i], 1u);
    if (pi < CAP) { nbr[i * CAP + pi] = (unsigned)j; val[i * CAP + pi] = vf; valr[i * CAP + pi] = vr; }
    unsigned pj = atomicAdd(&deg[j], 1u);
    if (pj < CAP) { nbr[j * CAP + pj] = (unsigned)i; val[j * CAP + pj] = vr; valr[j * CAP + pj] = vf; }
  }
}

__global__ void k_thresh(const unsigned* __restrict__ deg, const float* __restrict__ val,
                         float* __restrict__ thr) {
  int node = blockIdx.x * (blockDim.x >> 6) + (threadIdx.x >> 6);
  if (node >= N) return;
  int lane = threadIdx.x & 63;
  unsigned d = deg[node];
  if (d <= MAXDEG) {
    if (!lane) thr[node] = -INFINITY;
    return;
  }
  unsigned dc = d < CAP ? d : CAP;
  const float* v = val + (size_t)node * CAP;
  float best = INFINITY;
  for (unsigned s = lane; s < dc; s += 64) {
    float vs = v[s];
    unsigned cnt = 0;
    for (unsigned u = 0; u < dc; ++u) cnt += (v[u] > vs) ? 1u : 0u;
    if (cnt <= MAXDEG - 1) best = fminf(best, vs);
  }
  for (int off = 32; off; off >>= 1) best = fminf(best, __shfl_xor(best, off, 64));
  if (!lane) thr[node] = best;
}

__global__ void k_filter(const unsigned* __restrict__ deg, const float* __restrict__ thr,
                         unsigned* __restrict__ nbr, float* __restrict__ val,
                         float* __restrict__ valr, unsigned* __restrict__ degn) {
  int node = blockIdx.x * (blockDim.x >> 6) + (threadIdx.x >> 6);
  if (node >= N) return;
  int lane = threadIdx.x & 63;
  unsigned d = deg[node];
  unsigned dc = d < CAP ? d : CAP;
  float ti = thr[node];
  bool iok = (d <= MAXDEG);
  unsigned* nb = nbr + (size_t)node * CAP;
  float* vv = val + (size_t)node * CAP;
  float* vr = valr + (size_t)node * CAP;
  unsigned base = 0;
  for (unsigned r0 = 0; r0 < dc; r0 += 64) {
    unsigned s = r0 + lane;
    bool act = s < dc;
    unsigned j = 0;
    float v = 0.f, w = 0.f;
    bool keep = false;
    if (act) {
      j = nb[s]; v = vv[s]; w = vr[s];
      unsigned dj = deg[j];
      keep = (iok || v >= ti) && (dj <= MAXDEG || w >= thr[j]);
    }
    unsigned long long m = __ballot(keep ? 1 : 0);
    unsigned pos = base + (unsigned)__popcll(m & ((1ull << lane) - 1ull));
    if (keep) { nb[pos] = j; vv[pos] = v; vr[pos] = w; }
    base += (unsigned)__popcll(m);
  }
  if (!lane) degn[node] = base;
}

__global__ void k_copydeg(const unsigned* __restrict__ degn, unsigned* __restrict__ deg) {
  int i = blockIdx.x * blockDim.x + threadIdx.x;
  if (i < N) deg[i] = degn[i];
}

__global__ void k_compact(const unsigned* __restrict__ deg, const unsigned* __restrict__ nbr,
                          unsigned* __restrict__ wcnt, unsigned* __restrict__ wedges) {
  int node = blockIdx.x;
  int s = threadIdx.x; // 192 threads
  unsigned d = deg[node];
  if (d > CAP) d = CAP;
  bool pred = false;
  unsigned j = 0;
  if ((unsigned)s < d) {
    j = nbr[(size_t)node * CAP + s];
    pred = (j > (unsigned)node);
  }
  unsigned pos = waveAppend(wcnt, pred);
  if (pred && pos < KEDGES) wedges[pos] = ((unsigned)node << LOGN) | j;
}

__global__ void k_scatter(const unsigned* __restrict__ wcnt, const unsigned* __restrict__ wedges,
                          float* __restrict__ out) {
  unsigned t = blockIdx.x * blockDim.x + threadIdx.x;
  unsigned n = *wcnt;
  if (n > KEDGES) n = KEDGES;
  if (t < n) {
    unsigned e = wedges[t];
    unsigned i = e >> LOGN, j = e & NMASK;
    out[(size_t)i * N + j] = 1.0f;
    out[(size_t)j * N + i] = 1.0f;
  }
}

extern "C" void kernel_launch(void* const* d_in, const int* in_sizes, int n_in,
                              void* d_out, int out_size, void* d_ws, size_t ws_size,
                              hipStream_t stream) {
  (void)in_sizes; (void)n_in; (void)out_size;
  const float* A = (const float*)d_in[0];
  const float* LP = (const float*)d_in[1];
  float* out = (float*)d_out;
  char* B8 = (char*)d_out;

  Scal* sc = (Scal*)B8;
  unsigned short* lab = (unsigned short*)(B8 + OFF_LAB);
  unsigned* hist = (unsigned*)(B8 + OFF_HIST);
  unsigned* deg = (unsigned*)(B8 + OFF_DEG);
  unsigned* degn = (unsigned*)(B8 + OFF_DEGN);
  float* thr = (float*)(B8 + OFF_THR);
  unsigned* EQ = (unsigned*)(B8 + OFF_EQ);
  unsigned* EQA = (unsigned*)(B8 + OFF_EQA);
  uint2* Dl = (uint2*)(B8 + OFF_D);
  uint2* Cl = (uint2*)(B8 + OFF_C);
  unsigned* nbr = (unsigned*)(B8 + OFF_NBR);
  float* val = (float*)(B8 + OFF_VAL);
  float* valr = (float*)(B8 + OFF_VALR);

  // final edge list: prefer d_ws; fall back to the tail of d_in[0] (A is not
  // read after k_build, and the harness restores inputs before every launch)
  bool ws_ok = ws_size >= (size_t)(1024 + 4 * KEDGES);
  unsigned* wcnt = ws_ok ? (unsigned*)d_ws : (unsigned*)((char*)d_in[0] + (200u << 20));
  unsigned* wedges = wcnt + 256;

  hipMemsetAsync(B8, 0, 4096, stream);                  // scalars
  hipMemsetAsync(B8 + OFF_HIST, 0, 8192, stream);       // histogram
  hipMemsetAsync(B8 + OFF_DEG, 0, 32768, stream);       // degree counters
  hipMemsetAsync(wcnt, 0, 1024, stream);                // final edge counter

  k_labels<<<32, 256, 0, stream>>>(LP, lab);
  k_mass<<<4096, 256, 0, stream>>>(A, lab, sc);
  k_scal<<<1, 1, 0, stream>>>(sc);
  k_hist<<<dim3(NT, NT), 256, 0, stream>>>(A, lab, sc, hist);
  k_findbin<<<1, 64, 0, stream>>>(hist, sc);
  k_emit<<<dim3(NT, NT), 256, 0, stream>>>(A, lab, sc, Dl, Cl);
  hipMemsetAsync(B8 + OFF_HIST, 0, 8192, stream);
  k_midhist<<<1024, 256, 0, stream>>>(Cl, sc, hist);
  k_findmid<<<1, 64, 0, stream>>>(hist, sc);
  hipMemsetAsync(B8 + OFF_HIST, 0, 8192, stream);
  k_lowhist<<<1024, 256, 0, stream>>>(Cl, sc, hist);
  k_findlow<<<1, 64, 0, stream>>>(hist, sc);
  k_eqcollect<<<1024, 256, 0, stream>>>(Cl, sc, EQ);
  k_eqrank<<<1, 256, 0, stream>>>(EQ, sc, EQA);
  k_build<<<2048, 256, 0, stream>>>(A, Dl, Cl, EQ, EQA, sc, deg, nbr, val, valr);
  for (int it = 0; it < 10; ++it) {
    k_thresh<<<2048, 256, 0, stream>>>(deg, val, thr);
    k_filter<<<2048, 256, 0, stream>>>(deg, thr, nbr, val, valr, degn);
    k_copydeg<<<32, 256, 0, stream>>>(degn, deg);
  }
  k_compact<<<N, CAP, 0, stream>>>(deg, nbr, wcnt, wedges);
  hipMemsetAsync(d_out, 0, (size_t)N * N * sizeof(float), stream);
  k_scatter<<<(KEDGES + 255) / 256, 256, 0, stream>>>(wcnt, wedges, out);
}